// Round 9
// baseline (100.323 us; speedup 1.0000x reference)
//
#include <hip/hip_runtime.h>

// out[b,o,n] = sum_h W[n,o,h] * x[b,h,n] + bias[n,o]
// x: [16][32][50000] f32, W: [50000][32][32] f32, bias: [50000][32] f32
// Per node: D[o 32][b 16] = W_n . X_n via 2x mfma_f32_16x16x32_bf16.
// R9: persistent blocks, 4-5 contiguous 16-node tiles each, cross-tile
// software pipeline (x(t+1)->regs + W(t+1) prologue overlap epilogue(t)),
// raw s_barrier (no implicit vmcnt(0) drains) in the steady loop.

#define NN 50000
#define CH 32
#define TPB 256        // 4 waves; wave wv owns nodes wv*4..+3 of each tile
#define NXCD 8
#define NBLK 768       // 3 blocks/CU
#define EXTRA 53       // 3125 tiles = 768*4 + 53

typedef __attribute__((ext_vector_type(8))) short bf16x8;
typedef __attribute__((ext_vector_type(4))) float f32x4;
typedef __attribute__((ext_vector_type(4))) unsigned short bf16x4;
typedef float __attribute__((address_space(1))) gf32;
typedef float __attribute__((address_space(3))) lf32;

__device__ __forceinline__ unsigned short f2bf(float f) {
    union { float f; unsigned u; } v; v.f = f;
    return (unsigned short)((v.u + 0x7fffu + ((v.u >> 16) & 1u)) >> 16);
}

__global__ __launch_bounds__(TPB, 3)
void localconv1d_kernel(const float* __restrict__ x,
                        const float* __restrict__ W,
                        const float* __restrict__ bias,
                        float* __restrict__ out) {
    // LDS: [0,16K) x-tile bf16 frags (epilogue scratch overlays, tile-dead)
    //      [16K,32K) W dbuf: wave wv at +wv*4096, buf (s&1) at +2048
    //      [32K,42K) bias for all of this block's tiles
    __shared__ __align__(16) char smem[43008];
    unsigned short* xs   = (unsigned short*)smem;
    char*           wlds = smem + 16384;
    float*          blds = (float*)(smem + 32768);
    float*          scr  = (float*)smem;

    const int tid  = threadIdx.x;
    const int lane = tid & 63;
    const int wv   = tid >> 6;
    const int bl   = lane & 15;
    const int hc   = lane >> 4;

    // XCD swizzle (768 % 8 == 0 -> simple bijection)
    const int orig = blockIdx.x;
    const int bk   = (orig & 7) * (NBLK / NXCD) + (orig >> 3);

    const int T     = 4 + (bk < EXTRA);
    const int tbase = bk * 4 + (bk < EXTRA ? bk : EXTRA);

    const int lpermf = (lane * 4) ^ (((lane >> 3) & 7) << 2);
    const int chunk  = tid & 3;
    const int gib    = tid >> 2;

    float4 xr[2][4];

#define ISSUE_W(n0_, s_)                                                      \
    do {                                                                      \
        const float* src_ = W + (size_t)((n0_) + wv * 4 + ((s_) >> 1)) * 1024 \
                            + ((s_) & 1) * 512 + lpermf;                      \
        char* dst_ = wlds + wv * 4096 + ((s_) & 1) * 2048;                    \
        __builtin_amdgcn_global_load_lds((const gf32*)src_, (lf32*)dst_,      \
                                         16, 0, 0);                           \
        __builtin_amdgcn_global_load_lds((const gf32*)(src_ + 256),           \
                                         (lf32*)(dst_ + 1024), 16, 0, 0);     \
    } while (0)

#define LOADX(n0_)                                                            \
    do {                                                                      \
        _Pragma("unroll")                                                     \
        for (int u_ = 0; u_ < 2; ++u_) {                                      \
            _Pragma("unroll")                                                 \
            for (int k_ = 0; k_ < 4; ++k_)                                    \
                xr[u_][k_] = *reinterpret_cast<const float4*>(                \
                    x + (size_t)((gib + u_ * 64) * 4 + k_) * NN + (n0_)       \
                    + chunk * 4);                                             \
        }                                                                     \
    } while (0)

#define WRITEXS()                                                             \
    do {                                                                      \
        _Pragma("unroll")                                                     \
        for (int u_ = 0; u_ < 2; ++u_) {                                      \
            int gi_ = gib + u_ * 64;                                          \
            int b_  = gi_ >> 3;                                               \
            int h4_ = gi_ & 7;                                                \
            unsigned eb_ = (unsigned)((h4_ >> 1) * 256 + b_ * 16              \
                                      + (h4_ & 1) * 8);                       \
            _Pragma("unroll")                                                 \
            for (int c_ = 0; c_ < 4; ++c_) {                                  \
                int nn_ = chunk * 4 + c_;                                     \
                unsigned base_ = (unsigned)(nn_ * 1024) + eb_;                \
                base_ ^= ((unsigned)(nn_ >> 2) & 7u) << 4;                    \
                bf16x4 pk_;                                                   \
                pk_[0] = f2bf(xr[u_][0][c_]); pk_[1] = f2bf(xr[u_][1][c_]);   \
                pk_[2] = f2bf(xr[u_][2][c_]); pk_[3] = f2bf(xr[u_][3][c_]);   \
                *reinterpret_cast<bf16x4*>((char*)xs + base_) = pk_;          \
            }                                                                 \
        }                                                                     \
    } while (0)

#define BODY(s_)                                                              \
    do {                                                                      \
        const int g_  = (s_) >> 1;                                            \
        const int H_  = (s_) & 1;                                             \
        const int nn_ = wv * 4 + g_;                                          \
        const char* wb_ = wlds + wv * 4096 + ((s_) & 1) * 2048;               \
        const int slot_ = (bl * 8 + hc * 2) ^ (bl & 7);                       \
        f32x4 wlo_ = *reinterpret_cast<const f32x4*>(wb_ + slot_ * 16);       \
        f32x4 whi_ = *reinterpret_cast<const f32x4*>(wb_ + (slot_ ^ 1) * 16); \
        f32x4 cfr_ = *reinterpret_cast<const f32x4*>(                         \
            blds + (tl * 16 + nn_) * 32 + 16 * H_ + 4 * hc);                  \
        unsigned ra_ = (unsigned)(nn_ * 1024 + lane * 16);                    \
        ra_ ^= ((unsigned)(nn_ >> 2) & 7u) << 4;                              \
        bf16x8 bf_ = *reinterpret_cast<const bf16x8*>((const char*)xs + ra_); \
        bf16x8 af_;                                                           \
        af_[0] = f2bf(wlo_[0]); af_[1] = f2bf(wlo_[1]);                       \
        af_[2] = f2bf(wlo_[2]); af_[3] = f2bf(wlo_[3]);                       \
        af_[4] = f2bf(whi_[0]); af_[5] = f2bf(whi_[1]);                       \
        af_[6] = f2bf(whi_[2]); af_[7] = f2bf(whi_[3]);                       \
        acc[g_][H_] = __builtin_amdgcn_mfma_f32_16x16x32_bf16(af_, bf_,       \
                                                              cfr_, 0, 0, 0); \
    } while (0)

#define WAIT(imm_)                                                            \
    do { asm volatile("s_waitcnt vmcnt(" #imm_ ")" ::: "memory");             \
         __builtin_amdgcn_sched_barrier(0); } while (0)

#define BAR()                                                                 \
    do { asm volatile("s_waitcnt lgkmcnt(0)" ::: "memory");                   \
         __builtin_amdgcn_s_barrier();                                        \
         __builtin_amdgcn_sched_barrier(0); } while (0)

    // ---- block prologue: bias (all tiles) + x(t0) + W prologue ----
    {
        const int total_ = T * 512;
        #pragma unroll
        for (int j = 0; j < 3; ++j) {
            int off = j * 1024 + wv * 256;
            if (off < total_)
                __builtin_amdgcn_global_load_lds(
                    (const gf32*)(bias + (size_t)tbase * 512 + off + lane * 4),
                    (lf32*)(blds + off), 16, 0, 0);
        }
    }
    LOADX(tbase * 16);
    WRITEXS();                  // compiler waits xr as needed
    __syncthreads();            // full drain: bias + xs visible
    ISSUE_W(tbase * 16, 0);
    ISSUE_W(tbase * 16, 1);

    for (int tl = 0; tl < T; ++tl) {
        const int n0  = (tbase + tl) * 16;
        const bool hn = (tl + 1 < T);
        const int n0n = n0 + 16;
        f32x4 acc[4][2];

        WAIT(2); BODY(0); ISSUE_W(n0, 2);
        WAIT(2); BODY(1); ISSUE_W(n0, 3);
        WAIT(2); BODY(2); ISSUE_W(n0, 4);
        WAIT(2); BODY(3); ISSUE_W(n0, 5);
        WAIT(2); BODY(4); ISSUE_W(n0, 6);
        WAIT(2); BODY(5); ISSUE_W(n0, 7);
        __builtin_amdgcn_sched_barrier(0);
        if (hn) { LOADX(n0n); }           // issued LAST -> in-order vmcnt ok
        __builtin_amdgcn_sched_barrier(0);
        if (hn) {
            WAIT(10); BODY(6);            // retire W6; X(8)+W7(2) in flight
            WAIT(8);  BODY(7);            // retire W7; X(8) in flight
        } else {
            WAIT(2); BODY(6);
            WAIT(0); BODY(7);
        }
        BAR();                            // xs readers done; NO vmcnt drain
        if (hn) { ISSUE_W(n0n, 0); ISSUE_W(n0n, 1); }  // overlaps epilogue

        // ---- epilogue: transpose via scr (= dead xs region), stride 20 ----
        #pragma unroll
        for (int Hh = 0; Hh < 2; ++Hh) {
            #pragma unroll
            for (int bh = 0; bh < 2; ++bh) {
                if ((bl >> 3) == bh) {
                    #pragma unroll
                    for (int rr = 0; rr < 4; ++rr) {
                        int rp = (4 * hc + rr) * 8 + (bl & 7);
                        f32x4 v;
                        v[0] = acc[0][Hh][rr]; v[1] = acc[1][Hh][rr];
                        v[2] = acc[2][Hh][rr]; v[3] = acc[3][Hh][rr];
                        *reinterpret_cast<f32x4*>(scr + rp * 20 + wv * 4) = v;
                    }
                }
                BAR();
                #pragma unroll
                for (int it = 0; it < 2; ++it) {
                    int R  = tid >> 1;
                    int C4 = it * 2 + (tid & 1);
                    f32x4 v = *reinterpret_cast<const f32x4*>(
                        scr + R * 20 + C4 * 4);
                    *reinterpret_cast<f32x4*>(
                        out + ((size_t)(bh * 8 + (R & 7)) * CH
                               + Hh * 16 + (R >> 3)) * NN + n0 + C4 * 4) = v;
                }
                BAR();
            }
        }

        if (hn) {
            asm volatile("s_waitcnt vmcnt(0)" ::: "memory");  // X (+W prologue) landed
            __builtin_amdgcn_sched_barrier(0);
            WRITEXS();
            BAR();
        }
    }

#undef ISSUE_W
#undef LOADX
#undef WRITEXS
#undef BODY
#undef WAIT
#undef BAR
}

extern "C" void kernel_launch(void* const* d_in, const int* in_sizes, int n_in,
                              void* d_out, int out_size, void* d_ws, size_t ws_size,
                              hipStream_t stream) {
    const float* x    = (const float*)d_in[0];
    const float* W    = (const float*)d_in[1];
    const float* bias = (const float*)d_in[2];
    float* out        = (float*)d_out;

    localconv1d_kernel<<<NBLK, TPB, 0, stream>>>(x, W, bias, out);
}

// Round 10
// 99.164 us; speedup vs baseline: 1.0117x; 1.0117x over previous
//
#include <hip/hip_runtime.h>

// out[b,o,n] = sum_h W[n,o,h] * x[b,h,n] + bias[n,o]
// x: [16][32][50000] f32, W: [50000][32][32] f32, bias: [50000][32] f32
// Per node: D[o 32][b 16] = W_n . X_n via 2x mfma_f32_16x16x32_bf16.
// R10: NT=64 (256B x/out chunks per row per block), TPB=1024 (16 waves,
// 4 nodes/wave), R8's proven W-stream + frag layouts + transpose epilogue.

#define NN 50000
#define CH 32
#define NT 64          // nodes per block
#define TPB 1024       // 16 waves; wave wv owns nodes wv*4 .. wv*4+3
#define NXCD 8

typedef __attribute__((ext_vector_type(8))) short bf16x8;
typedef __attribute__((ext_vector_type(4))) float f32x4;
typedef __attribute__((ext_vector_type(4))) unsigned short bf16x4;
typedef float __attribute__((address_space(1))) gf32;
typedef float __attribute__((address_space(3))) lf32;

__device__ __forceinline__ unsigned short f2bf(float f) {
    union { float f; unsigned u; } v; v.f = f;
    return (unsigned short)((v.u + 0x7fffu + ((v.u >> 16) & 1u)) >> 16);
}

__global__ __launch_bounds__(TPB, 4)
void localconv1d_kernel(const float* __restrict__ x,
                        const float* __restrict__ W,
                        const float* __restrict__ bias,
                        float* __restrict__ out) {
    // LDS: [0,65536)        x-tile bf16 frags (64 nodes x 1KB); scr overlays
    //      [65536,131072)   W dbuf: wave wv at +wv*4096, buf (s&1) at +2048
    //      [131072,139264)  bias tile (2048 f32)
    __shared__ __align__(16) char smem[139264];
    unsigned short* xs   = (unsigned short*)smem;
    char*           wlds = smem + 65536;
    float*          blds = (float*)(smem + 131072);
    float*          scr  = (float*)smem;

    const int tid  = threadIdx.x;
    const int lane = tid & 63;
    const int wv   = tid >> 6;     // 0..15
    const int bl   = lane & 15;
    const int hc   = lane >> 4;

    // ---- bijective XCD-aware block swizzle (nwg = 782 = 8*97 + 6) ----
    const int nwg  = (NN + NT - 1) / NT;    // 782
    const int q    = nwg / NXCD;            // 97
    const int r    = nwg % NXCD;            // 6
    const int orig = blockIdx.x;
    const int xcd  = orig % NXCD;
    const int wgid = (xcd < r ? xcd * (q + 1) : r * (q + 1) + (xcd - r) * q)
                     + orig / NXCD;
    int n0 = wgid * NT;
    if (n0 > NN - NT) n0 = NN - NT;   // tail: overlap-recompute (identical dup writes)

    // ---- bias -> LDS: 8 KB, waves 0..7 issue 1 KB each ----
    if (wv < 8)
        __builtin_amdgcn_global_load_lds(
            (const gf32*)(bias + (size_t)n0 * CH + wv * 256 + lane * 4),
            (lf32*)(blds + wv * 256), 16, 0, 0);

    // ---- stage x -> LDS bf16 B-fragments (R5..R8-validated layout) ----
    {
        const int chunk = tid & 15;           // node group chunk*4 .. +3
        const int gib   = tid >> 4;           // 0..63
        float4 xv[2][4];
        #pragma unroll
        for (int u = 0; u < 2; ++u) {
            int gi = gib + u * 64;            // 0..127
            #pragma unroll
            for (int k = 0; k < 4; ++k) {
                int row = gi * 4 + k;         // b*32 + h
                xv[u][k] = *reinterpret_cast<const float4*>(
                    x + (size_t)row * NN + n0 + chunk * 4);
            }
        }
        #pragma unroll
        for (int u = 0; u < 2; ++u) {
            int gi = gib + u * 64;
            int b  = gi >> 3;                 // 0..15
            int h4 = gi & 7;
            unsigned eb = (unsigned)((h4 >> 1) * 256 + b * 16 + (h4 & 1) * 8);
            #pragma unroll
            for (int c = 0; c < 4; ++c) {
                int nn = chunk * 4 + c;       // 0..63
                unsigned base = (unsigned)(nn * 1024) + eb;
                base ^= ((unsigned)(nn >> 2) & 7u) << 4;
                bf16x4 pk;
                pk[0] = f2bf(xv[u][0][c]); pk[1] = f2bf(xv[u][1][c]);
                pk[2] = f2bf(xv[u][2][c]); pk[3] = f2bf(xv[u][3][c]);
                *reinterpret_cast<bf16x4*>((char*)xs + base) = pk;
            }
        }
    }
    __syncthreads();   // x + bias ready; vmcnt drained to 0 here

    // ---- W pipeline: step s = node(g=s>>1) x o-half(H=s&1), 2KB per step ----
    // Contiguous 1KB per instruction; within-128B XOR perm on the source so
    // the frag read below is a bank-spread swizzled ds_read_b128 (R8-proven).
    const int lpermf = (lane * 4) ^ (((lane >> 3) & 7) << 2);  // float offset
    #define ISSUE_W(s_)                                                          \
        do {                                                                     \
            int g_ = (s_) >> 1, H_ = (s_) & 1;                                   \
            const float* base_ = W + (size_t)(n0 + wv * 4 + g_) * 1024           \
                                 + H_ * 512;                                     \
            char* dst_ = wlds + wv * 4096 + ((s_) & 1) * 2048;                   \
            __builtin_amdgcn_global_load_lds((const gf32*)(base_ + lpermf),      \
                                             (lf32*)dst_, 16, 0, 0);             \
            __builtin_amdgcn_global_load_lds((const gf32*)(base_ + 256 + lpermf),\
                                             (lf32*)(dst_ + 1024), 16, 0, 0);    \
        } while (0)

    ISSUE_W(0);
    ISSUE_W(1);

    f32x4 acc[4][2];

    #pragma unroll
    for (int s = 0; s < 8; ++s) {
        if (s == 7) { asm volatile("s_waitcnt vmcnt(0)" ::: "memory"); }
        else        { asm volatile("s_waitcnt vmcnt(2)" ::: "memory"); }
        __builtin_amdgcn_sched_barrier(0);

        const int g  = s >> 1;
        const int Hh = s & 1;
        const int nn = wv * 4 + g;

        // A fragment: chunks f0 = bl*8 + hc*2, f1 = f0+1; slot = f ^ (bl&7)
        const char* wb = wlds + wv * 4096 + (s & 1) * 2048;
        const int slot0 = (bl * 8 + hc * 2) ^ (bl & 7);
        f32x4 wlo = *reinterpret_cast<const f32x4*>(wb + slot0 * 16);
        f32x4 whi = *reinterpret_cast<const f32x4*>(wb + (slot0 ^ 1) * 16);

        f32x4 cfr = *reinterpret_cast<const f32x4*>(blds + nn * 32 + 16 * Hh + 4 * hc);

        unsigned raddr = (unsigned)(nn * 1024 + lane * 16);
        raddr ^= ((unsigned)(nn >> 2) & 7u) << 4;
        bf16x8 bfrag = *reinterpret_cast<const bf16x8*>((const char*)xs + raddr);

        bf16x8 afrag;
        afrag[0] = f2bf(wlo[0]); afrag[1] = f2bf(wlo[1]);
        afrag[2] = f2bf(wlo[2]); afrag[3] = f2bf(wlo[3]);
        afrag[4] = f2bf(whi[0]); afrag[5] = f2bf(whi[1]);
        afrag[6] = f2bf(whi[2]); afrag[7] = f2bf(whi[3]);

        __builtin_amdgcn_sched_barrier(0);
        if (s + 2 < 8) ISSUE_W(s + 2);

        acc[g][Hh] = __builtin_amdgcn_mfma_f32_16x16x32_bf16(afrag, bfrag, cfr, 0, 0, 0);
    }

    // ---- epilogue: LDS transpose; stores are 128B-contiguous per row ----
    // scratch (overlays dead xs): 128 rows x stride 68 f32
    __syncthreads();

    #pragma unroll
    for (int Hh = 0; Hh < 2; ++Hh) {
        #pragma unroll
        for (int bh = 0; bh < 2; ++bh) {
            if ((bl >> 3) == bh) {
                #pragma unroll
                for (int rr = 0; rr < 4; ++rr) {
                    int rp = (4 * hc + rr) * 8 + (bl & 7);   // 0..127
                    f32x4 v;
                    v[0] = acc[0][Hh][rr]; v[1] = acc[1][Hh][rr];
                    v[2] = acc[2][Hh][rr]; v[3] = acc[3][Hh][rr];
                    *reinterpret_cast<f32x4*>(scr + rp * 68 + wv * 4) = v;
                }
            }
            __syncthreads();
            #pragma unroll
            for (int it = 0; it < 2; ++it) {
                int R  = tid >> 3;                 // 0..127
                int C4 = (tid & 7) + it * 8;       // 0..15
                f32x4 v = *reinterpret_cast<const f32x4*>(scr + R * 68 + C4 * 4);
                *reinterpret_cast<f32x4*>(
                    out + ((size_t)(bh * 8 + (R & 7)) * CH + Hh * 16 + (R >> 3)) * NN
                        + n0 + C4 * 4) = v;
            }
            __syncthreads();
        }
    }
}

extern "C" void kernel_launch(void* const* d_in, const int* in_sizes, int n_in,
                              void* d_out, int out_size, void* d_ws, size_t ws_size,
                              hipStream_t stream) {
    const float* x    = (const float*)d_in[0];
    const float* W    = (const float*)d_in[1];
    const float* bias = (const float*)d_in[2];
    float* out        = (float*)d_out;

    const int blocks = (NN + NT - 1) / NT;   // 782
    localconv1d_kernel<<<blocks, TPB, 0, stream>>>(x, W, bias, out);
}

// Round 12
// 82.106 us; speedup vs baseline: 1.2219x; 1.2078x over previous
//
#include <hip/hip_runtime.h>

// out[b,o,n] = sum_h W[n,o,h] * x[b,h,n] + bias[n,o]
// x: [16][32][50000] f32, W: [50000][32][32] f32, bias: [50000][32] f32
// Per node: D[o 32][b 16] = W_n . X_n via 2x mfma_f32_16x16x32_bf16.
// R12 = R8 + NONTEMPORAL epilogue stores (fixed: use ext_vector f32x4,
// not HIP_vector_type float4, for __builtin_nontemporal_store).

#define NN 50000
#define CH 32
#define NT 32          // nodes per block
#define TPB 512        // 8 waves; wave wv owns nodes wv*4 .. wv*4+3
#define NXCD 8

typedef __attribute__((ext_vector_type(8))) short bf16x8;
typedef __attribute__((ext_vector_type(4))) float f32x4;
typedef __attribute__((ext_vector_type(4))) unsigned short bf16x4;
typedef float __attribute__((address_space(1))) gf32;
typedef float __attribute__((address_space(3))) lf32;

__device__ __forceinline__ unsigned short f2bf(float f) {
    union { float f; unsigned u; } v; v.f = f;
    return (unsigned short)((v.u + 0x7fffu + ((v.u >> 16) & 1u)) >> 16);
}

__global__ __launch_bounds__(TPB, 4)
void localconv1d_kernel(const float* __restrict__ x,
                        const float* __restrict__ W,
                        const float* __restrict__ bias,
                        float* __restrict__ out) {
    // LDS carve: [0,32768) x-tile bf16 frags (reused as f32 scratch in epilogue)
    //            [32768,65536) W dbuf: wave wv at +wv*4096, buf at +(s&1)*2048
    //            [65536,69632) bias tile (1024 f32)
    __shared__ __align__(16) char smem[69632];
    unsigned short* xs   = (unsigned short*)smem;
    char*           wlds = smem + 32768;
    float*          blds = (float*)(smem + 65536);
    float*          scr  = (float*)smem;

    const int tid  = threadIdx.x;
    const int lane = tid & 63;
    const int wv   = tid >> 6;
    const int bl   = lane & 15;
    const int hc   = lane >> 4;

    // ---- bijective XCD-aware block swizzle (nwg = 1563 = 8*195 + 3) ----
    const int nwg  = (NN + NT - 1) / NT;
    const int q    = nwg / NXCD;
    const int r    = nwg % NXCD;
    const int orig = blockIdx.x;
    const int xcd  = orig % NXCD;
    const int wgid = (xcd < r ? xcd * (q + 1) : r * (q + 1) + (xcd - r) * q)
                     + orig / NXCD;
    int n0 = wgid * NT;
    if (n0 > NN - NT) n0 = NN - NT;   // tail: overlap-recompute (identical dup writes)

    // ---- bias -> LDS (drained at staging barrier; waves 0..3 only) ----
    if (wv < 4)
        __builtin_amdgcn_global_load_lds(
            (const gf32*)(bias + (size_t)n0 * CH + wv * 256 + lane * 4),
            (lf32*)(blds + wv * 256), 16, 0, 0);

    // ---- stage x -> LDS bf16 B-fragments (R5..R8-validated layout) ----
    {
        const int chunk = tid & 7;
        float4 xv[2][4];
        #pragma unroll
        for (int u = 0; u < 2; ++u) {
            int gi = (tid >> 3) + u * 64;             // 0..127
            #pragma unroll
            for (int k = 0; k < 4; ++k) {
                int row = gi * 4 + k;                 // b*32 + h
                xv[u][k] = *reinterpret_cast<const float4*>(
                    x + (size_t)row * NN + n0 + chunk * 4);
            }
        }
        #pragma unroll
        for (int u = 0; u < 2; ++u) {
            int gi = (tid >> 3) + u * 64;
            int b  = gi >> 3;
            int h4 = gi & 7;
            int hg = h4 >> 1;
            int jb = (h4 & 1) * 8;
            #pragma unroll
            for (int c = 0; c < 4; ++c) {
                int nn = chunk * 4 + c;
                unsigned base = (unsigned)(nn * 1024 + hg * 256 + b * 16 + jb);
                base ^= ((unsigned)(nn >> 2) & 7u) << 4;
                bf16x4 pk;
                pk[0] = f2bf(((const float*)&xv[u][0])[c]);
                pk[1] = f2bf(((const float*)&xv[u][1])[c]);
                pk[2] = f2bf(((const float*)&xv[u][2])[c]);
                pk[3] = f2bf(((const float*)&xv[u][3])[c]);
                *reinterpret_cast<bf16x4*>((char*)xs + base) = pk;
            }
        }
    }
    __syncthreads();   // x + bias ready; vmcnt drained to 0 here

    // ---- W pipeline: step s = node(g=s>>1) x o-half(H=s&1), 2KB per step ----
    // Contiguous 1KB per instruction; within-128B XOR perm on the source so
    // the frag read below is a bank-spread swizzled ds_read_b128 (R8-proven).
    const int lpermf = (lane * 4) ^ (((lane >> 3) & 7) << 2);  // float offset
    #define ISSUE_W(s_)                                                          \
        do {                                                                     \
            int g_ = (s_) >> 1, H_ = (s_) & 1;                                   \
            const float* base_ = W + (size_t)(n0 + wv * 4 + g_) * 1024           \
                                 + H_ * 512;                                     \
            char* dst_ = wlds + wv * 4096 + ((s_) & 1) * 2048;                   \
            __builtin_amdgcn_global_load_lds((const gf32*)(base_ + lpermf),      \
                                             (lf32*)dst_, 16, 0, 0);             \
            __builtin_amdgcn_global_load_lds((const gf32*)(base_ + 256 + lpermf),\
                                             (lf32*)(dst_ + 1024), 16, 0, 0);    \
        } while (0)

    ISSUE_W(0);
    ISSUE_W(1);

    f32x4 acc[4][2];

    #pragma unroll
    for (int s = 0; s < 8; ++s) {
        if (s == 7) { asm volatile("s_waitcnt vmcnt(0)" ::: "memory"); }
        else        { asm volatile("s_waitcnt vmcnt(2)" ::: "memory"); }
        __builtin_amdgcn_sched_barrier(0);

        const int g  = s >> 1;
        const int Hh = s & 1;
        const int nn = wv * 4 + g;

        // A fragment: chunks f0 = bl*8 + hc*2, f1 = f0+1; slot = f ^ (bl&7)
        const char* wb = wlds + wv * 4096 + (s & 1) * 2048;
        const int slot0 = (bl * 8 + hc * 2) ^ (bl & 7);
        f32x4 wlo = *reinterpret_cast<const f32x4*>(wb + slot0 * 16);
        f32x4 whi = *reinterpret_cast<const f32x4*>(wb + (slot0 ^ 1) * 16);

        f32x4 cfr = *reinterpret_cast<const f32x4*>(blds + nn * 32 + 16 * Hh + 4 * hc);

        unsigned raddr = (unsigned)(nn * 1024 + lane * 16);
        raddr ^= ((unsigned)(nn >> 2) & 7u) << 4;
        bf16x8 bfrag = *reinterpret_cast<const bf16x8*>((const char*)xs + raddr);

        bf16x8 afrag;
        afrag[0] = f2bf(wlo[0]); afrag[1] = f2bf(wlo[1]);
        afrag[2] = f2bf(wlo[2]); afrag[3] = f2bf(wlo[3]);
        afrag[4] = f2bf(whi[0]); afrag[5] = f2bf(whi[1]);
        afrag[6] = f2bf(whi[2]); afrag[7] = f2bf(whi[3]);

        __builtin_amdgcn_sched_barrier(0);
        if (s + 2 < 8) ISSUE_W(s + 2);

        acc[g][Hh] = __builtin_amdgcn_mfma_f32_16x16x32_bf16(afrag, bfrag, cfr, 0, 0, 0);
    }

    // ---- epilogue: LDS transpose; NONTEMPORAL 128B-line stores ----
    __syncthreads();

    #pragma unroll
    for (int Hh = 0; Hh < 2; ++Hh) {
        #pragma unroll
        for (int bh = 0; bh < 2; ++bh) {
            if ((bl >> 3) == bh) {
                #pragma unroll
                for (int rr = 0; rr < 4; ++rr) {
                    int rp = (4 * hc + rr) * 8 + (bl & 7);
                    f32x4 v;
                    v[0] = acc[0][Hh][rr];
                    v[1] = acc[1][Hh][rr];
                    v[2] = acc[2][Hh][rr];
                    v[3] = acc[3][Hh][rr];
                    *reinterpret_cast<f32x4*>(scr + rp * 36 + wv * 4) = v;
                }
            }
            __syncthreads();
            #pragma unroll
            for (int it = 0; it < 2; ++it) {
                int R = it * 64 + (tid >> 3);    // 0..127
                int C = tid & 7;
                int o15 = R >> 3, B = R & 7;
                f32x4 v = *reinterpret_cast<const f32x4*>(scr + R * 36 + C * 4);
                f32x4* dst = reinterpret_cast<f32x4*>(
                    out + ((size_t)(bh * 8 + B) * CH + Hh * 16 + o15) * NN
                        + n0 + C * 4);
                __builtin_nontemporal_store(v, dst);
            }
            __syncthreads();
        }
    }
}

extern "C" void kernel_launch(void* const* d_in, const int* in_sizes, int n_in,
                              void* d_out, int out_size, void* d_ws, size_t ws_size,
                              hipStream_t stream) {
    const float* x    = (const float*)d_in[0];
    const float* W    = (const float*)d_in[1];
    const float* bias = (const float*)d_in[2];
    float* out        = (float*)d_out;

    const int blocks = (NN + NT - 1) / NT;   // 1563
    localconv1d_kernel<<<blocks, TPB, 0, stream>>>(x, W, bias, out);
}

// Round 13
// 77.104 us; speedup vs baseline: 1.3011x; 1.0649x over previous
//
#include <hip/hip_runtime.h>

// out[b,o,n] = sum_h W[n,o,h] * x[b,h,n] + bias[n,o]
// x: [16][32][50000] f32, W: [50000][32][32] f32, bias: [50000][32] f32
// Per node: D[o 32][b 16] = W_n . X_n via 2x mfma_f32_16x16x32_bf16.
// R13 = R12 + NT cache policy (aux=2) on the W global_load_lds stream
// (205 MB/dispatch, zero reuse -> stop it churning L2/L3; out stores
// already nontemporal from R12).

#define NN 50000
#define CH 32
#define NT 32          // nodes per block
#define TPB 512        // 8 waves; wave wv owns nodes wv*4 .. wv*4+3
#define NXCD 8

typedef __attribute__((ext_vector_type(8))) short bf16x8;
typedef __attribute__((ext_vector_type(4))) float f32x4;
typedef __attribute__((ext_vector_type(4))) unsigned short bf16x4;
typedef float __attribute__((address_space(1))) gf32;
typedef float __attribute__((address_space(3))) lf32;

__device__ __forceinline__ unsigned short f2bf(float f) {
    union { float f; unsigned u; } v; v.f = f;
    return (unsigned short)((v.u + 0x7fffu + ((v.u >> 16) & 1u)) >> 16);
}

__global__ __launch_bounds__(TPB, 4)
void localconv1d_kernel(const float* __restrict__ x,
                        const float* __restrict__ W,
                        const float* __restrict__ bias,
                        float* __restrict__ out) {
    // LDS carve: [0,32768) x-tile bf16 frags (reused as f32 scratch in epilogue)
    //            [32768,65536) W dbuf: wave wv at +wv*4096, buf at +(s&1)*2048
    //            [65536,69632) bias tile (1024 f32)
    __shared__ __align__(16) char smem[69632];
    unsigned short* xs   = (unsigned short*)smem;
    char*           wlds = smem + 32768;
    float*          blds = (float*)(smem + 65536);
    float*          scr  = (float*)smem;

    const int tid  = threadIdx.x;
    const int lane = tid & 63;
    const int wv   = tid >> 6;
    const int bl   = lane & 15;
    const int hc   = lane >> 4;

    // ---- bijective XCD-aware block swizzle (nwg = 1563 = 8*195 + 3) ----
    const int nwg  = (NN + NT - 1) / NT;
    const int q    = nwg / NXCD;
    const int r    = nwg % NXCD;
    const int orig = blockIdx.x;
    const int xcd  = orig % NXCD;
    const int wgid = (xcd < r ? xcd * (q + 1) : r * (q + 1) + (xcd - r) * q)
                     + orig / NXCD;
    int n0 = wgid * NT;
    if (n0 > NN - NT) n0 = NN - NT;   // tail: overlap-recompute (identical dup writes)

    // ---- bias -> LDS (drained at staging barrier; waves 0..3 only) ----
    if (wv < 4)
        __builtin_amdgcn_global_load_lds(
            (const gf32*)(bias + (size_t)n0 * CH + wv * 256 + lane * 4),
            (lf32*)(blds + wv * 256), 16, 0, 0);

    // ---- stage x -> LDS bf16 B-fragments (R5..R8-validated layout) ----
    {
        const int chunk = tid & 7;
        float4 xv[2][4];
        #pragma unroll
        for (int u = 0; u < 2; ++u) {
            int gi = (tid >> 3) + u * 64;             // 0..127
            #pragma unroll
            for (int k = 0; k < 4; ++k) {
                int row = gi * 4 + k;                 // b*32 + h
                xv[u][k] = *reinterpret_cast<const float4*>(
                    x + (size_t)row * NN + n0 + chunk * 4);
            }
        }
        #pragma unroll
        for (int u = 0; u < 2; ++u) {
            int gi = (tid >> 3) + u * 64;
            int b  = gi >> 3;
            int h4 = gi & 7;
            int hg = h4 >> 1;
            int jb = (h4 & 1) * 8;
            #pragma unroll
            for (int c = 0; c < 4; ++c) {
                int nn = chunk * 4 + c;
                unsigned base = (unsigned)(nn * 1024 + hg * 256 + b * 16 + jb);
                base ^= ((unsigned)(nn >> 2) & 7u) << 4;
                bf16x4 pk;
                pk[0] = f2bf(((const float*)&xv[u][0])[c]);
                pk[1] = f2bf(((const float*)&xv[u][1])[c]);
                pk[2] = f2bf(((const float*)&xv[u][2])[c]);
                pk[3] = f2bf(((const float*)&xv[u][3])[c]);
                *reinterpret_cast<bf16x4*>((char*)xs + base) = pk;
            }
        }
    }
    __syncthreads();   // x + bias ready; vmcnt drained to 0 here

    // ---- W pipeline: step s = node(g=s>>1) x o-half(H=s&1), 2KB per step ----
    // Contiguous 1KB per instruction; within-128B XOR perm on the source so
    // the frag read below is a bank-spread swizzled ds_read_b128 (R8-proven).
    // aux=2 -> NT cache policy: W streams past L2/L3 without thrashing them.
    const int lpermf = (lane * 4) ^ (((lane >> 3) & 7) << 2);  // float offset
    #define ISSUE_W(s_)                                                          \
        do {                                                                     \
            int g_ = (s_) >> 1, H_ = (s_) & 1;                                   \
            const float* base_ = W + (size_t)(n0 + wv * 4 + g_) * 1024           \
                                 + H_ * 512;                                     \
            char* dst_ = wlds + wv * 4096 + ((s_) & 1) * 2048;                   \
            __builtin_amdgcn_global_load_lds((const gf32*)(base_ + lpermf),      \
                                             (lf32*)dst_, 16, 0, 2);             \
            __builtin_amdgcn_global_load_lds((const gf32*)(base_ + 256 + lpermf),\
                                             (lf32*)(dst_ + 1024), 16, 0, 2);    \
        } while (0)

    ISSUE_W(0);
    ISSUE_W(1);

    f32x4 acc[4][2];

    #pragma unroll
    for (int s = 0; s < 8; ++s) {
        if (s == 7) { asm volatile("s_waitcnt vmcnt(0)" ::: "memory"); }
        else        { asm volatile("s_waitcnt vmcnt(2)" ::: "memory"); }
        __builtin_amdgcn_sched_barrier(0);

        const int g  = s >> 1;
        const int Hh = s & 1;
        const int nn = wv * 4 + g;

        // A fragment: chunks f0 = bl*8 + hc*2, f1 = f0+1; slot = f ^ (bl&7)
        const char* wb = wlds + wv * 4096 + (s & 1) * 2048;
        const int slot0 = (bl * 8 + hc * 2) ^ (bl & 7);
        f32x4 wlo = *reinterpret_cast<const f32x4*>(wb + slot0 * 16);
        f32x4 whi = *reinterpret_cast<const f32x4*>(wb + (slot0 ^ 1) * 16);

        f32x4 cfr = *reinterpret_cast<const f32x4*>(blds + nn * 32 + 16 * Hh + 4 * hc);

        unsigned raddr = (unsigned)(nn * 1024 + lane * 16);
        raddr ^= ((unsigned)(nn >> 2) & 7u) << 4;
        bf16x8 bfrag = *reinterpret_cast<const bf16x8*>((const char*)xs + raddr);

        bf16x8 afrag;
        afrag[0] = f2bf(wlo[0]); afrag[1] = f2bf(wlo[1]);
        afrag[2] = f2bf(wlo[2]); afrag[3] = f2bf(wlo[3]);
        afrag[4] = f2bf(whi[0]); afrag[5] = f2bf(whi[1]);
        afrag[6] = f2bf(whi[2]); afrag[7] = f2bf(whi[3]);

        __builtin_amdgcn_sched_barrier(0);
        if (s + 2 < 8) ISSUE_W(s + 2);

        acc[g][Hh] = __builtin_amdgcn_mfma_f32_16x16x32_bf16(afrag, bfrag, cfr, 0, 0, 0);
    }

    // ---- epilogue: LDS transpose; NONTEMPORAL 128B-line stores ----
    __syncthreads();

    #pragma unroll
    for (int Hh = 0; Hh < 2; ++Hh) {
        #pragma unroll
        for (int bh = 0; bh < 2; ++bh) {
            if ((bl >> 3) == bh) {
                #pragma unroll
                for (int rr = 0; rr < 4; ++rr) {
                    int rp = (4 * hc + rr) * 8 + (bl & 7);
                    f32x4 v;
                    v[0] = acc[0][Hh][rr];
                    v[1] = acc[1][Hh][rr];
                    v[2] = acc[2][Hh][rr];
                    v[3] = acc[3][Hh][rr];
                    *reinterpret_cast<f32x4*>(scr + rp * 36 + wv * 4) = v;
                }
            }
            __syncthreads();
            #pragma unroll
            for (int it = 0; it < 2; ++it) {
                int R = it * 64 + (tid >> 3);    // 0..127
                int C = tid & 7;
                int o15 = R >> 3, B = R & 7;
                f32x4 v = *reinterpret_cast<const f32x4*>(scr + R * 36 + C * 4);
                f32x4* dst = reinterpret_cast<f32x4*>(
                    out + ((size_t)(bh * 8 + B) * CH + Hh * 16 + o15) * NN
                        + n0 + C * 4);
                __builtin_nontemporal_store(v, dst);
            }
            __syncthreads();
        }
    }
}

extern "C" void kernel_launch(void* const* d_in, const int* in_sizes, int n_in,
                              void* d_out, int out_size, void* d_ws, size_t ws_size,
                              hipStream_t stream) {
    const float* x    = (const float*)d_in[0];
    const float* W    = (const float*)d_in[1];
    const float* bias = (const float*)d_in[2];
    float* out        = (float*)d_out;

    const int blocks = (NN + NT - 1) / NT;   // 1563
    localconv1d_kernel<<<blocks, TPB, 0, stream>>>(x, W, bias, out);
}

// Round 14
// 76.855 us; speedup vs baseline: 1.3054x; 1.0032x over previous
//
#include <hip/hip_runtime.h>

// out[b,o,n] = sum_h W[n,o,h] * x[b,h,n] + bias[n,o]
// x: [16][32][50000] f32, W: [50000][32][32] f32, bias: [50000][32] f32
// Per node: D[o 32][b 16] = W_n . X_n via 2x mfma_f32_16x16x32_bf16.
// R14 = R13 + bfrag hoist to VGPRs (frees xs region) -> QUAD-buffered W
// pipeline (prefetch depth 4) at unchanged LDS/occupancy (2 blocks/CU).

#define NN 50000
#define CH 32
#define NT 32          // nodes per block
#define TPB 512        // 8 waves; wave wv owns nodes wv*4 .. wv*4+3
#define NXCD 8

typedef __attribute__((ext_vector_type(8))) short bf16x8;
typedef __attribute__((ext_vector_type(4))) float f32x4;
typedef __attribute__((ext_vector_type(4))) unsigned short bf16x4;
typedef float __attribute__((address_space(1))) gf32;
typedef float __attribute__((address_space(3))) lf32;

__device__ __forceinline__ unsigned short f2bf(float f) {
    union { float f; unsigned u; } v; v.f = f;
    return (unsigned short)((v.u + 0x7fffu + ((v.u >> 16) & 1u)) >> 16);
}

__global__ __launch_bounds__(TPB, 4)
void localconv1d_kernel(const float* __restrict__ x,
                        const float* __restrict__ W,
                        const float* __restrict__ bias,
                        float* __restrict__ out) {
    // LDS carve: [0,32768)     x-tile bf16 frags; after per-wave bfrag hoist,
    //                          wave wv's 4KB becomes W buffers 2,3
    //            [32768,65536) W buffers 0,1 (wave wv at +wv*4096); epilogue scr
    //            [65536,69632) bias tile (1024 f32)
    __shared__ __align__(16) char smem[69632];
    unsigned short* xs   = (unsigned short*)smem;
    char*           wlds = smem + 32768;
    float*          blds = (float*)(smem + 65536);
    float*          scr  = (float*)(smem + 32768);

    const int tid  = threadIdx.x;
    const int lane = tid & 63;
    const int wv   = tid >> 6;
    const int bl   = lane & 15;
    const int hc   = lane >> 4;

    // ---- bijective XCD-aware block swizzle (nwg = 1563 = 8*195 + 3) ----
    const int nwg  = (NN + NT - 1) / NT;
    const int q    = nwg / NXCD;
    const int r    = nwg % NXCD;
    const int orig = blockIdx.x;
    const int xcd  = orig % NXCD;
    const int wgid = (xcd < r ? xcd * (q + 1) : r * (q + 1) + (xcd - r) * q)
                     + orig / NXCD;
    int n0 = wgid * NT;
    if (n0 > NN - NT) n0 = NN - NT;   // tail: overlap-recompute (identical dup writes)

    // ---- bias -> LDS (drained at staging barrier; waves 0..3 only) ----
    if (wv < 4)
        __builtin_amdgcn_global_load_lds(
            (const gf32*)(bias + (size_t)n0 * CH + wv * 256 + lane * 4),
            (lf32*)(blds + wv * 256), 16, 0, 0);

    // ---- stage x -> LDS bf16 B-fragments (R5..R13-validated layout) ----
    {
        const int chunk = tid & 7;
        float4 xv[2][4];
        #pragma unroll
        for (int u = 0; u < 2; ++u) {
            int gi = (tid >> 3) + u * 64;             // 0..127
            #pragma unroll
            for (int k = 0; k < 4; ++k) {
                int row = gi * 4 + k;                 // b*32 + h
                xv[u][k] = *reinterpret_cast<const float4*>(
                    x + (size_t)row * NN + n0 + chunk * 4);
            }
        }
        #pragma unroll
        for (int u = 0; u < 2; ++u) {
            int gi = (tid >> 3) + u * 64;
            int b  = gi >> 3;
            int h4 = gi & 7;
            int hg = h4 >> 1;
            int jb = (h4 & 1) * 8;
            #pragma unroll
            for (int c = 0; c < 4; ++c) {
                int nn = chunk * 4 + c;
                unsigned base = (unsigned)(nn * 1024 + hg * 256 + b * 16 + jb);
                base ^= ((unsigned)(nn >> 2) & 7u) << 4;
                bf16x4 pk;
                pk[0] = f2bf(((const float*)&xv[u][0])[c]);
                pk[1] = f2bf(((const float*)&xv[u][1])[c]);
                pk[2] = f2bf(((const float*)&xv[u][2])[c]);
                pk[3] = f2bf(((const float*)&xv[u][3])[c]);
                *reinterpret_cast<bf16x4*>((char*)xs + base) = pk;
            }
        }
    }
    __syncthreads();   // x + bias ready; vmcnt drained to 0 here

    // ---- hoist this wave's 4 B-fragments to VGPRs; its xs 4KB goes dead ----
    bf16x8 bfr[4];
    #pragma unroll
    for (int g = 0; g < 4; ++g) {
        int nn = wv * 4 + g;
        unsigned ra = (unsigned)(nn * 1024 + lane * 16);
        ra ^= ((unsigned)(nn >> 2) & 7u) << 4;
        bfr[g] = *reinterpret_cast<const bf16x8*>((const char*)xs + ra);
    }
    asm volatile("s_waitcnt lgkmcnt(0)" ::: "memory");   // reads done BEFORE
    __builtin_amdgcn_sched_barrier(0);                   // xs reuse as W bufs

    // ---- W quad-buffer pipeline: step s = node(s>>1) x o-half(s&1) ----
    // bufs 0,1 in wlds; bufs 2,3 overlay this wave's dead xs slice.
    // Contiguous 1KB per load, within-128B XOR source perm (R8-proven),
    // aux=2 (NT policy, R13-proven).
    const int lpermf = (lane * 4) ^ (((lane >> 3) & 7) << 2);  // float offset
#define WBUF(i_) ((((i_) & 3) < 2 ? wlds : (char*)xs) + wv * 4096 + ((i_) & 1) * 2048)
#define ISSUE_W(s_)                                                          \
    do {                                                                     \
        const float* base_ = W + (size_t)(n0 + wv * 4 + ((s_) >> 1)) * 1024  \
                             + ((s_) & 1) * 512;                             \
        char* dst_ = WBUF(s_);                                               \
        __builtin_amdgcn_global_load_lds((const gf32*)(base_ + lpermf),      \
                                         (lf32*)dst_, 16, 0, 2);             \
        __builtin_amdgcn_global_load_lds((const gf32*)(base_ + 256 + lpermf),\
                                         (lf32*)(dst_ + 1024), 16, 0, 2);    \
    } while (0)

    ISSUE_W(0); ISSUE_W(1); ISSUE_W(2); ISSUE_W(3);   // depth 4 in flight

    f32x4 acc[4][2];

#define STEP(s_, v_)                                                          \
    do {                                                                      \
        asm volatile("s_waitcnt vmcnt(" #v_ ")" ::: "memory");                \
        __builtin_amdgcn_sched_barrier(0);                                    \
        const int g_ = (s_) >> 1, H_ = (s_) & 1;                              \
        const int nn_ = wv * 4 + g_;                                          \
        const char* wb_ = WBUF(s_);                                           \
        const int slot_ = (bl * 8 + hc * 2) ^ (bl & 7);                       \
        f32x4 wlo_ = *reinterpret_cast<const f32x4*>(wb_ + slot_ * 16);       \
        f32x4 whi_ = *reinterpret_cast<const f32x4*>(wb_ + (slot_ ^ 1) * 16); \
        f32x4 cfr_ = *reinterpret_cast<const f32x4*>(                         \
            blds + nn_ * 32 + 16 * H_ + 4 * hc);                              \
        bf16x8 af_;                                                           \
        af_[0] = f2bf(wlo_[0]); af_[1] = f2bf(wlo_[1]);                       \
        af_[2] = f2bf(wlo_[2]); af_[3] = f2bf(wlo_[3]);                       \
        af_[4] = f2bf(whi_[0]); af_[5] = f2bf(whi_[1]);                       \
        af_[6] = f2bf(whi_[2]); af_[7] = f2bf(whi_[3]);                       \
        asm volatile("s_waitcnt lgkmcnt(0)" ::: "memory");                    \
        __builtin_amdgcn_sched_barrier(0);                                    \
        if ((s_) + 4 < 8) ISSUE_W((s_) + 4);                                  \
        acc[g_][H_] = __builtin_amdgcn_mfma_f32_16x16x32_bf16(                \
            af_, bfr[g_], cfr_, 0, 0, 0);                                     \
    } while (0)

    STEP(0, 6); STEP(1, 6); STEP(2, 6); STEP(3, 6);
    STEP(4, 6); STEP(5, 4); STEP(6, 2); STEP(7, 0);

#undef STEP
#undef ISSUE_W
#undef WBUF

    // ---- epilogue: LDS transpose (scr = dead W-buf-0/1 region);
    //      NONTEMPORAL 128B-line stores (R12-proven) ----
    __syncthreads();

    #pragma unroll
    for (int Hh = 0; Hh < 2; ++Hh) {
        #pragma unroll
        for (int bh = 0; bh < 2; ++bh) {
            if ((bl >> 3) == bh) {
                #pragma unroll
                for (int rr = 0; rr < 4; ++rr) {
                    int rp = (4 * hc + rr) * 8 + (bl & 7);
                    f32x4 v;
                    v[0] = acc[0][Hh][rr];
                    v[1] = acc[1][Hh][rr];
                    v[2] = acc[2][Hh][rr];
                    v[3] = acc[3][Hh][rr];
                    *reinterpret_cast<f32x4*>(scr + rp * 36 + wv * 4) = v;
                }
            }
            __syncthreads();
            #pragma unroll
            for (int it = 0; it < 2; ++it) {
                int R = it * 64 + (tid >> 3);    // 0..127
                int C = tid & 7;
                int o15 = R >> 3, B = R & 7;
                f32x4 v = *reinterpret_cast<const f32x4*>(scr + R * 36 + C * 4);
                f32x4* dst = reinterpret_cast<f32x4*>(
                    out + ((size_t)(bh * 8 + B) * CH + Hh * 16 + o15) * NN
                        + n0 + C * 4);
                __builtin_nontemporal_store(v, dst);
            }
            __syncthreads();
        }
    }
}

extern "C" void kernel_launch(void* const* d_in, const int* in_sizes, int n_in,
                              void* d_out, int out_size, void* d_ws, size_t ws_size,
                              hipStream_t stream) {
    const float* x    = (const float*)d_in[0];
    const float* W    = (const float*)d_in[1];
    const float* bias = (const float*)d_in[2];
    float* out        = (float*)d_out;

    const int blocks = (NN + NT - 1) / NT;   // 1563
    localconv1d_kernel<<<blocks, TPB, 0, stream>>>(x, W, bias, out);
}